// Round 2
// baseline (315.318 us; speedup 1.0000x reference)
//
#include <hip/hip_runtime.h>
#include <hip/hip_cooperative_groups.h>
#include <math.h>

namespace cg = cooperative_groups;

#define L_LEN  262144          // L = 2^18 = 512*512
#define NST    64
#define TPB    256
#define NBLK   512             // one column/row per block, 2 blocks/CU
#define TSTR   544             // padded row stride (float2) for transpose staging
#define PI2F   6.2831853071795864769f
#define PIF    3.1415926535897932385f

__device__ inline float2 cmul(float2 a, float2 b) {
    return make_float2(a.x*b.x - a.y*b.y, a.x*b.y + a.y*b.x);
}
__device__ inline float frcp(float x) { return __builtin_amdgcn_rcpf(x); }

// NF independent length-M FFTs in LDS, radix-4 Stockham + final radix-2.
// Layout buf[f*M+i]; natural in/out; sgn=-1 fwd, +1 inv (unscaled).
// Starts and ends with __syncthreads().
template<int M, int NF>
__device__ float2* lds_fft_r4(float2* b0, float2* b1, float sgn) {
    float2* src = b0; float2* dst = b1;
    int Ns = 1;
    while (Ns * 4 <= M) {
        __syncthreads();
        const int NB = NF * (M / 4);
        for (int bi = threadIdx.x; bi < NB; bi += TPB) {
            int f = bi / (M / 4);
            int j = bi & (M / 4 - 1);
            int r = j & (Ns - 1);
            const float2* s = src + f * M;
            float2 x0 = s[j];
            float2 x1 = s[j +     (M/4)];
            float2 x2 = s[j + 2 * (M/4)];
            float2 x3 = s[j + 3 * (M/4)];
            float ang = sgn * PI2F * ((float)r / (float)(4 * Ns));
            float sn, cs; __sincosf(ang, &sn, &cs);
            float2 w1 = make_float2(cs, sn);
            float2 w2 = cmul(w1, w1);
            float2 w3 = cmul(w2, w1);
            x1 = cmul(x1, w1); x2 = cmul(x2, w2); x3 = cmul(x3, w3);
            float2 t0 = make_float2(x0.x + x2.x, x0.y + x2.y);
            float2 t1 = make_float2(x0.x - x2.x, x0.y - x2.y);
            float2 t2 = make_float2(x1.x + x3.x, x1.y + x3.y);
            float2 t3 = make_float2(x1.x - x3.x, x1.y - x3.y);
            float2* d = dst + f * M + ((j - r) << 2) + r;
            d[0]      = make_float2(t0.x + t2.x, t0.y + t2.y);
            d[Ns]     = make_float2(t1.x - sgn * t3.y, t1.y + sgn * t3.x);
            d[2 * Ns] = make_float2(t0.x - t2.x, t0.y - t2.y);
            d[3 * Ns] = make_float2(t1.x + sgn * t3.y, t1.y - sgn * t3.x);
        }
        float2* t = src; src = dst; dst = t;
        Ns <<= 2;
    }
    if (Ns < M) {
        __syncthreads();
        const int NB = NF * (M / 2);
        for (int bi = threadIdx.x; bi < NB; bi += TPB) {
            int f = bi / (M / 2);
            int j = bi & (M / 2 - 1);
            const float2* s = src + f * M;
            float2 a = s[j];
            float2 b = s[j + M / 2];
            float ang = sgn * PI2F * ((float)j / (float)M);
            float sn, cs; __sincosf(ang, &sn, &cs);
            float2 wb = make_float2(cs * b.x - sn * b.y, cs * b.y + sn * b.x);
            float2* d = dst + f * M + j;
            d[0]     = make_float2(a.x + wb.x, a.y + wb.y);
            d[M / 2] = make_float2(a.x - wb.x, a.y - wb.y);
        }
        float2* t = src; src = dst; dst = t;
    }
    __syncthreads();
    return src;
}

// Single fused cooperative kernel: 512 blocks, 1 column/row each, 3 grid syncs.
// Phase1: atroots (512 pts/block) + A pass1 -> T_K ; u,u*tw pass1 -> T_U,T_Uo
// Phase2: K ifft pass2 -> K -> K*tw fwd pass1 -> T_Ko ; U pass2 -> Ue,Uo
// Phase3: Ko pass2 + Ve=Ue*A, Vo=Uo*Ko + inv pass1 -> T_Ve,T_Vo
// Phase4: inv pass2 + combine + D*u -> out
__global__ __launch_bounds__(TPB, 2) void fused(
    const float* __restrict__ u,
    const float* __restrict__ Lre, const float* __restrict__ Lim,
    const float* __restrict__ Pre, const float* __restrict__ Pim,
    const float* __restrict__ Bre, const float* __restrict__ Bim,
    const float* __restrict__ Cri, const float* __restrict__ lstp,
    const float* __restrict__ Dp, float* __restrict__ out,
    float2* __restrict__ Acm, float2* __restrict__ T_K,
    float2* __restrict__ T_U, float2* __restrict__ T_Uo,
    float2* __restrict__ T_Ko, float2* __restrict__ Ue, float2* __restrict__ Uo,
    float2* __restrict__ T_Ve, float2* __restrict__ T_Vo)
{
    __shared__ float2 b0[1024], b1[1024];
    __shared__ float4 cA[NST], cB[NST], cC[NST], cD[NST];
    cg::grid_group grid = cg::this_grid();
    const int t = threadIdx.x;
    const int c = blockIdx.x;                 // column (ph1) / row (ph2-4)
    const float invL = 1.0f / (float)L_LEN;

    // ================= Phase 1 =================
    if (t < NST) {
        float lr = Lre[t], li = Lim[t];
        float pr = Pre[t], pi = Pim[t];
        float br = Bre[t], bi = Bim[t];
        float cr = Cri[2*t], ci = Cri[2*t+1];
        float dx = -lr;
        float v00x = cr*br + ci*bi, v00y = cr*bi - ci*br;   // conj(C)*B
        float v01x = cr*pr + ci*pi, v01y = cr*pi - ci*pr;   // conj(C)*P
        float v10x = pr*br + pi*bi, v10y = pr*bi - pi*br;   // conj(P)*B
        float v11x = pr*pr + pi*pi;                         // conj(P)*P
        cA[t] = make_float4(li, dx*dx, dx*v11x, -v11x);
        cB[t] = make_float4(dx*v00x, v00y, dx*v00y, -v00x);
        cC[t] = make_float4(dx*v01x, v01y, dx*v01y, -v01x);
        cD[t] = make_float4(dx*v10x, v10y, dx*v10y, -v10x);
    }
    __syncthreads();
    {
        float G2 = 2.0f / expf(lstp[0]);
        float tn[2], gi[2], acc[2][8];
        #pragma unroll
        for (int p = 0; p < 2; ++p) {
            int e = t + (p << 8);
            int m = c + (e << 9);
            float h = PIF * ((float)m * invL);
            float sn, cs; __sincosf(h, &sn, &cs);
            float tv = sn * frcp(cs);
            tv = fminf(fmaxf(tv, -1e7f), 1e7f);  // pole guard (m=L/2: cos==0)
            tn[p] = tv; gi[p] = G2 * tv;
            #pragma unroll
            for (int q = 0; q < 8; ++q) acc[p][q] = 0.f;
        }
        #pragma unroll 2
        for (int n = 0; n < NST; ++n) {
            float4 a = cA[n], b = cB[n], cc = cC[n], d = cD[n];
            #pragma unroll
            for (int p = 0; p < 2; ++p) {
                float dy   = gi[p] - a.x;
                float iv   = frcp(fmaf(dy, dy, a.y));
                float ivdy = iv * dy;
                acc[p][6] = fmaf(iv, a.z, acc[p][6]);
                acc[p][7] = fmaf(ivdy, a.w, acc[p][7]);
                acc[p][0] = fmaf(iv, b.x,  fmaf(ivdy, b.y,  acc[p][0]));
                acc[p][1] = fmaf(iv, b.z,  fmaf(ivdy, b.w,  acc[p][1]));
                acc[p][2] = fmaf(iv, cc.x, fmaf(ivdy, cc.y, acc[p][2]));
                acc[p][3] = fmaf(iv, cc.z, fmaf(ivdy, cc.w, acc[p][3]));
                acc[p][4] = fmaf(iv, d.x,  fmaf(ivdy, d.y,  acc[p][4]));
                acc[p][5] = fmaf(iv, d.z,  fmaf(ivdy, d.w,  acc[p][5]));
            }
        }
        // prefetch u column (hidden under A FFT below)
        float uv0 = u[c + (t << 9)];
        float uv1 = u[c + ((t + 256) << 9)];
        #pragma unroll
        for (int p = 0; p < 2; ++p) {
            int e = t + (p << 8);
            float ax = 1.f + acc[p][6], ay = acc[p][7];
            float im = frcp(ax*ax + ay*ay);
            float tx = acc[p][2]*acc[p][4] - acc[p][3]*acc[p][5];
            float ty = acc[p][2]*acc[p][5] + acc[p][3]*acc[p][4];
            float wx = acc[p][0] - (tx*ax + ty*ay) * im;
            float wy = acc[p][1] - (ty*ax - tx*ay) * im;
            float2 A = make_float2(wx - tn[p]*wy, wy + tn[p]*wx); // (1+i*tan)*w
            Acm[(c << 9) + e] = A;                 // contiguous store
            b0[e] = A;
        }
        float2* rA = lds_fft_r4<512, 1>(b0, b1, +1.f);
        for (int k = t; k < 512; k += TPB) {
            float ang = PI2F * ((float)(c * k) * invL);
            float sn, cs; __sincosf(ang, &sn, &cs);
            T_K[k * TSTR + c] = cmul(make_float2(cs, sn), rA[k]);
        }
        __syncthreads();                           // rA consumed before reuse
        {
            int n0 = c + (t << 9), n1 = c + ((t + 256) << 9);
            float sn, cs;
            __sincosf(PIF * ((float)n0 * invL), &sn, &cs);
            b0[t]        = make_float2(uv0, 0.f);
            b0[512 + t]  = make_float2(uv0 * cs, -uv0 * sn);
            __sincosf(PIF * ((float)n1 * invL), &sn, &cs);
            b0[t + 256]       = make_float2(uv1, 0.f);
            b0[512 + t + 256] = make_float2(uv1 * cs, -uv1 * sn);
        }
        float2* rU = lds_fft_r4<512, 2>(b0, b1, -1.f);
        for (int i = t; i < 1024; i += TPB) {
            int v = i >> 9, k = i & 511;
            float ang = -PI2F * ((float)(c * k) * invL);
            float sn, cs; __sincosf(ang, &sn, &cs);
            float2 val = cmul(make_float2(cs, sn), rU[(v << 9) + k]);
            if (v == 0) T_U [k * TSTR + c] = val;
            else        T_Uo[k * TSTR + c] = val;
        }
    }
    grid.sync();

    // ================= Phase 2 =================
    {
        // prefetch U row (hidden under the two K FFTs)
        float2 pu0 = T_U [c * TSTR + t];
        float2 pu1 = T_U [c * TSTR + t + 256];
        float2 po0 = T_Uo[c * TSTR + t];
        float2 po1 = T_Uo[c * TSTR + t + 256];
        for (int i = t; i < 512; i += TPB) b0[i] = T_K[c * TSTR + i];
        float2* rK = lds_fft_r4<512, 1>(b0, b1, +1.f);
        float2* o = (rK == b0) ? b1 : b0;
        for (int i = t; i < 512; i += TPB) {
            int n = c + (i << 9);
            float K = rK[i].x * invL;                 // Re(ifft)/L
            float sn, cs; __sincosf(PIF * ((float)n * invL), &sn, &cs);
            o[i] = make_float2(K * cs, -K * sn);      // K * e^{-i pi n/L}
        }
        float2* r2 = lds_fft_r4<512, 1>(o, rK, -1.f);
        for (int k = t; k < 512; k += TPB) {
            float ang = -PI2F * ((float)(c * k) * invL);
            float sn, cs; __sincosf(ang, &sn, &cs);
            T_Ko[k * TSTR + c] = cmul(make_float2(cs, sn), r2[k]);
        }
        __syncthreads();                              // r2 consumed before reuse
        b0[t]             = pu0;
        b0[t + 256]       = pu1;
        b0[512 + t]       = po0;
        b0[512 + t + 256] = po1;
        float2* rUU = lds_fft_r4<512, 2>(b0, b1, -1.f);
        for (int i = t; i < 1024; i += TPB) {
            int v = i >> 9, k2 = i & 511;
            (v ? Uo : Ue)[(c << 9) + k2] = rUU[i];    // contiguous
        }
    }
    grid.sync();

    // ================= Phase 3 =================
    {
        // prefetch rows (hidden under Ko FFT)
        float2 qe0 = Ue [(c << 9) + t],  qe1 = Ue [(c << 9) + t + 256];
        float2 qo0 = Uo [(c << 9) + t],  qo1 = Uo [(c << 9) + t + 256];
        float2 qa0 = Acm[(c << 9) + t],  qa1 = Acm[(c << 9) + t + 256];
        for (int i = t; i < 512; i += TPB) b0[i] = T_Ko[c * TSTR + i];
        float2* rKo = lds_fft_r4<512, 1>(b0, b1, -1.f);
        float2* o3 = (rKo == b0) ? b1 : b0;
        o3[t]             = cmul(qe0, qa0);   // Ve (Ue Hermitian => Herm(A) ok)
        o3[t + 256]       = cmul(qe1, qa1);
        o3[512 + t]       = cmul(qo0, rKo[t]);        // Vo
        o3[512 + t + 256] = cmul(qo1, rKo[t + 256]);
        float2* rV = lds_fft_r4<512, 2>(o3, rKo, +1.f);
        for (int i = t; i < 1024; i += TPB) {
            int v = i >> 9, k = i & 511;
            float ang = PI2F * ((float)(c * k) * invL);
            float sn, cs; __sincosf(ang, &sn, &cs);
            float2 val = cmul(make_float2(cs, sn), rV[(v << 9) + k]);
            if (v == 0) T_Ve[k * TSTR + c] = val;
            else        T_Vo[k * TSTR + c] = val;
        }
    }
    grid.sync();

    // ================= Phase 4 =================
    {
        float un0 = u[c + (t << 9)];
        float un1 = u[c + ((t + 256) << 9)];
        const float D = Dp[0];
        for (int i = t; i < 512; i += TPB) {
            b0[i]       = T_Ve[c * TSTR + i];
            b0[i + 512] = T_Vo[c * TSTR + i];
        }
        float2* rY = lds_fft_r4<512, 2>(b0, b1, +1.f);  // [0,512)=yE, rest yO
        const float sc = 0.5f * invL;                   // 1/(2L)
        #pragma unroll
        for (int p = 0; p < 2; ++p) {
            int o1 = t + (p << 8);
            int n = c + (o1 << 9);
            float sn, cs; __sincosf(PIF * ((float)n * invL), &sn, &cs);
            float2 yE = rY[o1];
            float2 yO = rY[o1 + 512];
            float uv = p ? un1 : un0;
            // y = (yE.re + Re(e^{+i pi n/L} * yO)) / (2L) + D*u
            out[n] = fmaf(D, uv, (yE.x + cs * yO.x - sn * yO.y) * sc);
        }
    }
}

extern "C" void kernel_launch(void* const* d_in, const int* in_sizes, int n_in,
                              void* d_out, int out_size, void* d_ws, size_t ws_size,
                              hipStream_t stream) {
    const float* u    = (const float*)d_in[0];
    const float* Lre  = (const float*)d_in[1];
    const float* Lim  = (const float*)d_in[2];
    const float* Pre  = (const float*)d_in[3];
    const float* Pim  = (const float*)d_in[4];
    const float* Bre  = (const float*)d_in[5];
    const float* Bim  = (const float*)d_in[6];
    const float* Cri  = (const float*)d_in[7];
    const float* Dp   = (const float*)d_in[8];
    const float* lstp = (const float*)d_in[9];
    float* out = (float*)d_out;

    // Workspace (~19.7 MB): 512-stride arrays 2MB each; TSTR arrays 0x220000 each
    char* ws = (char*)d_ws;
    float2* Acm  = (float2*)(ws);                    // 512-stride
    float2* Ue   = (float2*)(ws + 0x200000);         // 512-stride
    float2* Uo   = (float2*)(ws + 0x400000);         // 512-stride
    float2* T_K  = (float2*)(ws + 0x600000);         // TSTR-stride
    float2* T_U  = (float2*)(ws + 0x820000);         // TSTR-stride
    float2* T_Uo = (float2*)(ws + 0xA40000);         // TSTR-stride
    float2* T_Ko = (float2*)(ws + 0xC60000);         // TSTR-stride
    float2* T_Ve = (float2*)(ws + 0xE80000);         // TSTR-stride
    float2* T_Vo = (float2*)(ws + 0x10A0000);        // TSTR-stride

    void* args[] = {
        (void*)&u, (void*)&Lre, (void*)&Lim, (void*)&Pre, (void*)&Pim,
        (void*)&Bre, (void*)&Bim, (void*)&Cri, (void*)&lstp, (void*)&Dp,
        (void*)&out,
        (void*)&Acm, (void*)&T_K, (void*)&T_U, (void*)&T_Uo,
        (void*)&T_Ko, (void*)&Ue, (void*)&Uo, (void*)&T_Ve, (void*)&T_Vo
    };
    hipLaunchCooperativeKernel(reinterpret_cast<void*>(fused),
                               dim3(NBLK), dim3(TPB), args, 0, stream);
}

// Round 3
// 114.816 us; speedup vs baseline: 2.7463x; 2.7463x over previous
//
#include <hip/hip_runtime.h>
#include <math.h>

#define L_LEN  262144          // L = 2^18 = 512*512
#define NST    64
#define TPB    256
#define TSTR   544             // padded row stride (float2) for transpose staging
#define PI2F   6.2831853071795864769f
#define PIF    3.1415926535897932385f

__device__ inline float2 cmul(float2 a, float2 b) {
    return make_float2(a.x*b.x - a.y*b.y, a.x*b.y + a.y*b.x);
}
__device__ inline float frcp(float x) { return __builtin_amdgcn_rcpf(x); }

// NF independent length-M FFTs in LDS, radix-4 Stockham + final radix-2.
// Layout buf[f*M+i]; natural in/out; sgn=-1 fwd, +1 inv (unscaled).
// Starts and ends with __syncthreads().
template<int M, int NF>
__device__ float2* lds_fft_r4(float2* b0, float2* b1, float sgn) {
    float2* src = b0; float2* dst = b1;
    int Ns = 1;
    while (Ns * 4 <= M) {
        __syncthreads();
        const int NB = NF * (M / 4);
        for (int bi = threadIdx.x; bi < NB; bi += TPB) {
            int f = bi / (M / 4);
            int j = bi & (M / 4 - 1);
            int r = j & (Ns - 1);
            const float2* s = src + f * M;
            float2 x0 = s[j];
            float2 x1 = s[j +     (M/4)];
            float2 x2 = s[j + 2 * (M/4)];
            float2 x3 = s[j + 3 * (M/4)];
            float ang = sgn * PI2F * ((float)r / (float)(4 * Ns));
            float sn, cs; __sincosf(ang, &sn, &cs);
            float2 w1 = make_float2(cs, sn);
            float2 w2 = cmul(w1, w1);
            float2 w3 = cmul(w2, w1);
            x1 = cmul(x1, w1); x2 = cmul(x2, w2); x3 = cmul(x3, w3);
            float2 t0 = make_float2(x0.x + x2.x, x0.y + x2.y);
            float2 t1 = make_float2(x0.x - x2.x, x0.y - x2.y);
            float2 t2 = make_float2(x1.x + x3.x, x1.y + x3.y);
            float2 t3 = make_float2(x1.x - x3.x, x1.y - x3.y);
            float2* d = dst + f * M + ((j - r) << 2) + r;
            d[0]      = make_float2(t0.x + t2.x, t0.y + t2.y);
            d[Ns]     = make_float2(t1.x - sgn * t3.y, t1.y + sgn * t3.x);
            d[2 * Ns] = make_float2(t0.x - t2.x, t0.y - t2.y);
            d[3 * Ns] = make_float2(t1.x + sgn * t3.y, t1.y - sgn * t3.x);
        }
        float2* t = src; src = dst; dst = t;
        Ns <<= 2;
    }
    if (Ns < M) {
        __syncthreads();
        const int NB = NF * (M / 2);
        for (int bi = threadIdx.x; bi < NB; bi += TPB) {
            int f = bi / (M / 2);
            int j = bi & (M / 2 - 1);
            const float2* s = src + f * M;
            float2 a = s[j];
            float2 b = s[j + M / 2];
            float ang = sgn * PI2F * ((float)j / (float)M);
            float sn, cs; __sincosf(ang, &sn, &cs);
            float2 wb = make_float2(cs * b.x - sn * b.y, cs * b.y + sn * b.x);
            float2* d = dst + f * M + j;
            d[0]     = make_float2(a.x + wb.x, a.y + wb.y);
            d[M / 2] = make_float2(a.x - wb.x, a.y - wb.y);
        }
        float2* t = src; src = dst; dst = t;
    }
    __syncthreads();
    return src;
}

// ---- kI: 1024 blocks.
//  b in [0,512): column c=b: pole/atroots (512 pts, 2/thread) + Acm store
//                + A ifft pass1 (NF=1) -> T_K scatter.
//  b in [512,1024): column c=b-512: u & u*tw fwd pass1 (NF=2) -> T_U, T_Uo.
__global__ __launch_bounds__(TPB, 4) void kI(
    const float* __restrict__ u,
    const float* __restrict__ Lre, const float* __restrict__ Lim,
    const float* __restrict__ Pre, const float* __restrict__ Pim,
    const float* __restrict__ Bre, const float* __restrict__ Bim,
    const float* __restrict__ Cri, const float* __restrict__ lstp,
    float2* __restrict__ Acm, float2* __restrict__ T_K,
    float2* __restrict__ T_U, float2* __restrict__ T_Uo)
{
    __shared__ float2 b0[1024], b1[1024];
    __shared__ float4 cA[NST], cB[NST], cC[NST], cD[NST];
    const int t = threadIdx.x, bx = blockIdx.x;
    const float invL = 1.0f / (float)L_LEN;
    if (bx < 512) {
        const int c = bx;
        if (t < NST) {
            float lr = Lre[t], li = Lim[t];
            float pr = Pre[t], pi = Pim[t];
            float br = Bre[t], bi = Bim[t];
            float cr = Cri[2*t], ci = Cri[2*t+1];
            float dx = -lr;
            float v00x = cr*br + ci*bi, v00y = cr*bi - ci*br;   // conj(C)*B
            float v01x = cr*pr + ci*pi, v01y = cr*pi - ci*pr;   // conj(C)*P
            float v10x = pr*br + pi*bi, v10y = pr*bi - pi*br;   // conj(P)*B
            float v11x = pr*pr + pi*pi;                         // conj(P)*P
            cA[t] = make_float4(li, dx*dx, dx*v11x, -v11x);
            cB[t] = make_float4(dx*v00x, v00y, dx*v00y, -v00x);
            cC[t] = make_float4(dx*v01x, v01y, dx*v01y, -v01x);
            cD[t] = make_float4(dx*v10x, v10y, dx*v10y, -v10x);
        }
        __syncthreads();
        float G2 = 2.0f / expf(lstp[0]);
        float tn[2], gi[2], acc[2][8];
        #pragma unroll
        for (int p = 0; p < 2; ++p) {
            int e = t + (p << 8);
            int m = c + (e << 9);
            float h = PIF * ((float)m * invL);
            float sn, cs; __sincosf(h, &sn, &cs);
            float tv = sn * frcp(cs);
            tv = fminf(fmaxf(tv, -1e7f), 1e7f);  // pole guard (m=L/2: cos==0)
            tn[p] = tv; gi[p] = G2 * tv;
            #pragma unroll
            for (int q = 0; q < 8; ++q) acc[p][q] = 0.f;
        }
        #pragma unroll 2
        for (int n = 0; n < NST; ++n) {
            float4 a = cA[n], b = cB[n], cc = cC[n], d = cD[n];
            #pragma unroll
            for (int p = 0; p < 2; ++p) {
                float dy   = gi[p] - a.x;
                float iv   = frcp(fmaf(dy, dy, a.y));
                float ivdy = iv * dy;
                acc[p][6] = fmaf(iv, a.z, acc[p][6]);
                acc[p][7] = fmaf(ivdy, a.w, acc[p][7]);
                acc[p][0] = fmaf(iv, b.x,  fmaf(ivdy, b.y,  acc[p][0]));
                acc[p][1] = fmaf(iv, b.z,  fmaf(ivdy, b.w,  acc[p][1]));
                acc[p][2] = fmaf(iv, cc.x, fmaf(ivdy, cc.y, acc[p][2]));
                acc[p][3] = fmaf(iv, cc.z, fmaf(ivdy, cc.w, acc[p][3]));
                acc[p][4] = fmaf(iv, d.x,  fmaf(ivdy, d.y,  acc[p][4]));
                acc[p][5] = fmaf(iv, d.z,  fmaf(ivdy, d.w,  acc[p][5]));
            }
        }
        #pragma unroll
        for (int p = 0; p < 2; ++p) {
            int e = t + (p << 8);
            float ax = 1.f + acc[p][6], ay = acc[p][7];
            float im = frcp(ax*ax + ay*ay);
            float tx = acc[p][2]*acc[p][4] - acc[p][3]*acc[p][5];
            float ty = acc[p][2]*acc[p][5] + acc[p][3]*acc[p][4];
            float wx = acc[p][0] - (tx*ax + ty*ay) * im;
            float wy = acc[p][1] - (ty*ax - tx*ay) * im;
            float2 A = make_float2(wx - tn[p]*wy, wy + tn[p]*wx); // (1+i*tan)*w
            Acm[(c << 9) + e] = A;                 // contiguous store
            b0[e] = A;
        }
        float2* rA = lds_fft_r4<512, 1>(b0, b1, +1.f);
        for (int k = t; k < 512; k += TPB) {
            float ang = PI2F * ((float)(c * k) * invL);
            float sn, cs; __sincosf(ang, &sn, &cs);
            T_K[k * TSTR + c] = cmul(make_float2(cs, sn), rA[k]);
        }
    } else {
        const int c = bx - 512;
        float uv0 = u[c + (t << 9)];
        float uv1 = u[c + ((t + 256) << 9)];
        {
            int n0 = c + (t << 9), n1 = c + ((t + 256) << 9);
            float sn, cs;
            __sincosf(PIF * ((float)n0 * invL), &sn, &cs);
            b0[t]        = make_float2(uv0, 0.f);
            b0[512 + t]  = make_float2(uv0 * cs, -uv0 * sn);
            __sincosf(PIF * ((float)n1 * invL), &sn, &cs);
            b0[t + 256]       = make_float2(uv1, 0.f);
            b0[512 + t + 256] = make_float2(uv1 * cs, -uv1 * sn);
        }
        float2* rU = lds_fft_r4<512, 2>(b0, b1, -1.f);
        for (int i = t; i < 1024; i += TPB) {
            int v = i >> 9, k = i & 511;
            float ang = -PI2F * ((float)(c * k) * invL);
            float sn, cs; __sincosf(ang, &sn, &cs);
            float2 val = cmul(make_float2(cs, sn), rU[(v << 9) + k]);
            if (v == 0) T_U [k * TSTR + c] = val;
            else        T_Uo[k * TSTR + c] = val;
        }
    }
}

// ---- kII: 1536 blocks.
//  b in [0,512): row c=b: T_K p2 (ifft) -> K -> K*tw -> fwd p1 -> T_Ko scatter.
//  b in [512,1024): row c=b-512: T_U p2 -> Ue (contiguous).
//  b in [1024,1536): row c=b-1024: T_Uo p2 -> Uo (contiguous).
__global__ __launch_bounds__(TPB, 6) void kII(
    const float2* __restrict__ T_K, const float2* __restrict__ T_U,
    const float2* __restrict__ T_Uo,
    float2* __restrict__ T_Ko, float2* __restrict__ Ue, float2* __restrict__ Uo)
{
    __shared__ float2 b0[1024], b1[1024];
    const int t = threadIdx.x, bx = blockIdx.x;
    const float invL = 1.0f / (float)L_LEN;
    if (bx < 512) {
        const int c = bx;
        for (int i = t; i < 512; i += TPB) b0[i] = T_K[c * TSTR + i];
        float2* rK = lds_fft_r4<512, 1>(b0, b1, +1.f);
        float2* o = (rK == b0) ? b1 : b0;
        for (int i = t; i < 512; i += TPB) {
            int n = c + (i << 9);
            float K = rK[i].x * invL;                 // Re(ifft)/L
            float sn, cs; __sincosf(PIF * ((float)n * invL), &sn, &cs);
            o[i] = make_float2(K * cs, -K * sn);      // K * e^{-i pi n/L}
        }
        float2* r2 = lds_fft_r4<512, 1>(o, rK, -1.f);
        for (int k = t; k < 512; k += TPB) {
            float ang = -PI2F * ((float)(c * k) * invL);
            float sn, cs; __sincosf(ang, &sn, &cs);
            T_Ko[k * TSTR + c] = cmul(make_float2(cs, sn), r2[k]);
        }
    } else {
        const int c = (bx & 511);
        const float2* Tin = (bx < 1024) ? T_U : T_Uo;
        float2* Xo        = (bx < 1024) ? Ue  : Uo;
        for (int i = t; i < 512; i += TPB) b0[i] = Tin[c * TSTR + i];
        float2* r = lds_fft_r4<512, 1>(b0, b1, -1.f);
        for (int k = t; k < 512; k += TPB)
            Xo[(c << 9) + k] = r[k];                  // contiguous
    }
}

// ---- kIII: 1024 blocks.
//  b in [0,512): row kc=b: T_Ko p2 -> Ko ; Vo = Uo*Ko ; inv p1 -> T_Vo scatter.
//  b in [512,1024): row kc=b-512: Ve = Ue*Acm ; inv p1 -> T_Ve scatter.
__global__ __launch_bounds__(TPB, 4) void kIII(
    const float2* __restrict__ T_Ko, const float2* __restrict__ Ue,
    const float2* __restrict__ Uo, const float2* __restrict__ Acm,
    float2* __restrict__ T_Ve, float2* __restrict__ T_Vo)
{
    __shared__ float2 b0[1024], b1[1024];
    const int t = threadIdx.x, bx = blockIdx.x;
    const float invL = 1.0f / (float)L_LEN;
    if (bx < 512) {
        const int kc = bx;
        for (int i = t; i < 512; i += TPB) b0[i] = T_Ko[kc * TSTR + i];
        float2* rKo = lds_fft_r4<512, 1>(b0, b1, -1.f);
        float2* o3 = (rKo == b0) ? b1 : b0;
        for (int i = t; i < 512; i += TPB)
            o3[i] = cmul(Uo[(kc << 9) + i], rKo[i]);  // Vo
        float2* rV = lds_fft_r4<512, 1>(o3, rKo, +1.f);
        for (int k = t; k < 512; k += TPB) {
            float ang = PI2F * ((float)(kc * k) * invL);
            float sn, cs; __sincosf(ang, &sn, &cs);
            T_Vo[k * TSTR + kc] = cmul(make_float2(cs, sn), rV[k]);
        }
    } else {
        const int kc = bx - 512;
        for (int i = t; i < 512; i += TPB)
            b0[i] = cmul(Ue[(kc << 9) + i], Acm[(kc << 9) + i]); // Ve
        float2* rV = lds_fft_r4<512, 1>(b0, b1, +1.f);
        for (int k = t; k < 512; k += TPB) {
            float ang = PI2F * ((float)(kc * k) * invL);
            float sn, cs; __sincosf(ang, &sn, &cs);
            T_Ve[k * TSTR + kc] = cmul(make_float2(cs, sn), rV[k]);
        }
    }
}

// ---- kIV: 512 blocks, one row k/block: inv pass2 (NF=2) + combine + D*u -> out
__global__ __launch_bounds__(TPB) void kIV(
    const float2* __restrict__ T_Ve, const float2* __restrict__ T_Vo,
    const float* __restrict__ u, const float* __restrict__ Dp,
    float* __restrict__ out)
{
    __shared__ float2 b0[1024], b1[1024];
    const int t = threadIdx.x, k = blockIdx.x;
    const float invL = 1.0f / (float)L_LEN;
    for (int i = t; i < 512; i += TPB) {
        b0[i]       = T_Ve[k * TSTR + i];                   // contiguous
        b0[i + 512] = T_Vo[k * TSTR + i];
    }
    float2* r = lds_fft_r4<512, 2>(b0, b1, +1.f);           // [0,512)=yE, rest yO
    const float sc = 0.5f * invL;                           // 1/(2L)
    const float D = Dp[0];
    for (int o1 = t; o1 < 512; o1 += TPB) {
        int n = k + (o1 << 9);
        float sn, cs; __sincosf(PIF * ((float)n * invL), &sn, &cs);
        float2 yE = r[o1];
        float2 yO = r[o1 + 512];
        // y = (yE.re + Re(e^{+i pi n/L} * yO)) / (2L) + D*u
        out[n] = fmaf(D, u[n], (yE.x + cs * yO.x - sn * yO.y) * sc);
    }
}

extern "C" void kernel_launch(void* const* d_in, const int* in_sizes, int n_in,
                              void* d_out, int out_size, void* d_ws, size_t ws_size,
                              hipStream_t stream) {
    const float* u    = (const float*)d_in[0];
    const float* Lre  = (const float*)d_in[1];
    const float* Lim  = (const float*)d_in[2];
    const float* Pre  = (const float*)d_in[3];
    const float* Pim  = (const float*)d_in[4];
    const float* Bre  = (const float*)d_in[5];
    const float* Bim  = (const float*)d_in[6];
    const float* Cri  = (const float*)d_in[7];
    const float* Dp   = (const float*)d_in[8];
    const float* lstp = (const float*)d_in[9];
    float* out = (float*)d_out;

    // Workspace (~19.7 MB): 512-stride arrays 2MB each; TSTR arrays 0x220000 each
    char* ws = (char*)d_ws;
    float2* Acm  = (float2*)(ws);                    // 512-stride
    float2* Ue   = (float2*)(ws + 0x200000);         // 512-stride
    float2* Uo   = (float2*)(ws + 0x400000);         // 512-stride
    float2* T_K  = (float2*)(ws + 0x600000);         // TSTR-stride
    float2* T_U  = (float2*)(ws + 0x820000);         // TSTR-stride
    float2* T_Uo = (float2*)(ws + 0xA40000);         // TSTR-stride
    float2* T_Ko = (float2*)(ws + 0xC60000);         // TSTR-stride
    float2* T_Ve = (float2*)(ws + 0xE80000);         // TSTR-stride
    float2* T_Vo = (float2*)(ws + 0x10A0000);        // TSTR-stride

    kI  <<<1024, TPB, 0, stream>>>(u, Lre,Lim,Pre,Pim,Bre,Bim,Cri,lstp,
                                   Acm, T_K, T_U, T_Uo);
    kII <<<1536, TPB, 0, stream>>>(T_K, T_U, T_Uo, T_Ko, Ue, Uo);
    kIII<<<1024, TPB, 0, stream>>>(T_Ko, Ue, Uo, Acm, T_Ve, T_Vo);
    kIV <<< 512, TPB, 0, stream>>>(T_Ve, T_Vo, u, Dp, out);
}

// Round 4
// 114.785 us; speedup vs baseline: 2.7470x; 1.0003x over previous
//
#include <hip/hip_runtime.h>
#include <math.h>

#define L_LEN  262144          // L = 2^18 = 512*512
#define NST    64
#define TPB    256
#define TSTR   544             // padded row stride (float2) for transpose staging
#define PI2F   6.2831853071795864769f
#define PIF    3.1415926535897932385f
#define R2C    0.70710678118654752440f

__device__ inline float2 cmul(float2 a, float2 b) {
    return make_float2(a.x*b.x - a.y*b.y, a.x*b.y + a.y*b.x);
}
__device__ inline float frcp(float x) { return __builtin_amdgcn_rcpf(x); }
__device__ inline float2 cadd(float2 a, float2 b) { return make_float2(a.x+b.x, a.y+b.y); }
__device__ inline float2 csub(float2 a, float2 b) { return make_float2(a.x-b.x, a.y-b.y); }

// Twiddle table (sign-agnostic, 576 float2 = 4.6KB):
//  [0,64):   (cos,sin) of 2*pi*r*q/64  , r=i>>3, q=i&7   (stage Ns=8)
//  [64,576): (cos,sin) of 2*pi*r*q/512 , r=ii>>3, q=ii&7 (stage Ns=64)
__device__ inline void twt_init(float2* twt) {
    for (int i = threadIdx.x; i < 576; i += TPB) {
        float ang;
        if (i < 64) ang = PI2F * (float)((i >> 3) * (i & 7)) * (1.0f / 64.0f);
        else { int ii = i - 64;
               ang = PI2F * (float)((ii >> 3) * (ii & 7)) * (1.0f / 512.0f); }
        float sn, cs; __sincosf(ang, &sn, &cs);
        twt[i] = make_float2(cs, sn);
    }
}

// NF independent length-512 FFTs in LDS, radix-8 Stockham (3 stages).
// Layout buf[f*512+i]; natural in/out; sgn=-1 fwd, +1 inv (unscaled).
// Twiddles: table lookup, w = (c, sgn*s). Starts/ends with __syncthreads().
template<int M, int NF>
__device__ float2* lds_fft_r8(float2* b0, float2* b1, float sgn, const float2* twt) {
    float2* src = b0; float2* dst = b1;
    for (int Ns = 1; Ns * 8 <= M; Ns <<= 3) {
        __syncthreads();
        const int NB = NF * (M / 8);
        for (int bi = threadIdx.x; bi < NB; bi += TPB) {
            int f = bi / (M / 8);
            int j = bi & (M / 8 - 1);
            int r = j & (Ns - 1);
            const float2* s = src + f * M;
            float2 x[8];
            #pragma unroll
            for (int q = 0; q < 8; ++q) x[q] = s[j + q * (M / 8)];
            if (Ns > 1) {
                const float2* tw = twt + ((Ns == 8) ? 0 : 64) + (r << 3);
                #pragma unroll
                for (int q = 1; q < 8; ++q) {
                    float2 w = tw[q];
                    float wc = w.x, ws = sgn * w.y;
                    x[q] = make_float2(x[q].x*wc - x[q].y*ws,
                                       x[q].x*ws + x[q].y*wc);
                }
            }
            // 8-pt DFT, kernel e^{sgn*2pi*i*pq/8}
            float2 E[4], O[4];
            {   // even inputs x0,x2,x4,x6
                float2 t0 = cadd(x[0], x[4]), t1 = csub(x[0], x[4]);
                float2 t2 = cadd(x[2], x[6]), t3 = csub(x[2], x[6]);
                E[0] = cadd(t0, t2); E[2] = csub(t0, t2);
                float2 it3 = make_float2(-sgn * t3.y, sgn * t3.x);
                E[1] = cadd(t1, it3); E[3] = csub(t1, it3);
            }
            {   // odd inputs x1,x3,x5,x7
                float2 t0 = cadd(x[1], x[5]), t1 = csub(x[1], x[5]);
                float2 t2 = cadd(x[3], x[7]), t3 = csub(x[3], x[7]);
                O[0] = cadd(t0, t2); O[2] = csub(t0, t2);
                float2 it3 = make_float2(-sgn * t3.y, sgn * t3.x);
                O[1] = cadd(t1, it3); O[3] = csub(t1, it3);
            }
            // combine: y_p = E_p + w8^p O_p ; y_{p+4} = E_p - w8^p O_p
            float2 w1o = make_float2(R2C * (O[1].x - sgn * O[1].y),
                                     R2C * (sgn * O[1].x + O[1].y));
            float2 w2o = make_float2(-sgn * O[2].y, sgn * O[2].x);
            float2 w3o = make_float2(R2C * (-O[3].x - sgn * O[3].y),
                                     R2C * (sgn * O[3].x - O[3].y));
            float2* d = dst + f * M + ((j - r) << 3) + r;
            d[0]      = cadd(E[0], O[0]);
            d[Ns]     = cadd(E[1], w1o);
            d[2 * Ns] = cadd(E[2], w2o);
            d[3 * Ns] = cadd(E[3], w3o);
            d[4 * Ns] = csub(E[0], O[0]);
            d[5 * Ns] = csub(E[1], w1o);
            d[6 * Ns] = csub(E[2], w2o);
            d[7 * Ns] = csub(E[3], w3o);
        }
        float2* tswp = src; src = dst; dst = tswp;
    }
    __syncthreads();
    return src;
}

// ---- kI: 1024 blocks.
//  b in [0,512): column c=b: pole/atroots (512 pts, 2/thread) + Acm store
//                + A ifft pass1 (NF=1) -> T_K scatter.
//  b in [512,1024): column c=b-512: u & u*tw fwd pass1 (NF=2) -> T_U, T_Uo.
__global__ __launch_bounds__(TPB, 4) void kI(
    const float* __restrict__ u,
    const float* __restrict__ Lre, const float* __restrict__ Lim,
    const float* __restrict__ Pre, const float* __restrict__ Pim,
    const float* __restrict__ Bre, const float* __restrict__ Bim,
    const float* __restrict__ Cri, const float* __restrict__ lstp,
    float2* __restrict__ Acm, float2* __restrict__ T_K,
    float2* __restrict__ T_U, float2* __restrict__ T_Uo)
{
    __shared__ float2 b0[1024], b1[1024];
    __shared__ float2 twt[576];
    __shared__ float4 cA[NST], cB[NST], cC[NST], cD[NST];
    const int t = threadIdx.x, bx = blockIdx.x;
    const float invL = 1.0f / (float)L_LEN;
    twt_init(twt);
    if (bx < 512) {
        const int c = bx;
        if (t < NST) {
            float lr = Lre[t], li = Lim[t];
            float pr = Pre[t], pi = Pim[t];
            float br = Bre[t], bi = Bim[t];
            float cr = Cri[2*t], ci = Cri[2*t+1];
            float dx = -lr;
            float v00x = cr*br + ci*bi, v00y = cr*bi - ci*br;   // conj(C)*B
            float v01x = cr*pr + ci*pi, v01y = cr*pi - ci*pr;   // conj(C)*P
            float v10x = pr*br + pi*bi, v10y = pr*bi - pi*br;   // conj(P)*B
            float v11x = pr*pr + pi*pi;                         // conj(P)*P
            cA[t] = make_float4(li, dx*dx, dx*v11x, -v11x);
            cB[t] = make_float4(dx*v00x, v00y, dx*v00y, -v00x);
            cC[t] = make_float4(dx*v01x, v01y, dx*v01y, -v01x);
            cD[t] = make_float4(dx*v10x, v10y, dx*v10y, -v10x);
        }
        __syncthreads();
        float G2 = 2.0f / expf(lstp[0]);
        float tn[2], gi[2], acc[2][8];
        #pragma unroll
        for (int p = 0; p < 2; ++p) {
            int e = t + (p << 8);
            int m = c + (e << 9);
            float h = PIF * ((float)m * invL);
            float sn, cs; __sincosf(h, &sn, &cs);
            float tv = sn * frcp(cs);
            tv = fminf(fmaxf(tv, -1e7f), 1e7f);  // pole guard (m=L/2: cos==0)
            tn[p] = tv; gi[p] = G2 * tv;
            #pragma unroll
            for (int q = 0; q < 8; ++q) acc[p][q] = 0.f;
        }
        #pragma unroll 2
        for (int n = 0; n < NST; ++n) {
            float4 a = cA[n], b = cB[n], cc = cC[n], d = cD[n];
            #pragma unroll
            for (int p = 0; p < 2; ++p) {
                float dy   = gi[p] - a.x;
                float iv   = frcp(fmaf(dy, dy, a.y));
                float ivdy = iv * dy;
                acc[p][6] = fmaf(iv, a.z, acc[p][6]);
                acc[p][7] = fmaf(ivdy, a.w, acc[p][7]);
                acc[p][0] = fmaf(iv, b.x,  fmaf(ivdy, b.y,  acc[p][0]));
                acc[p][1] = fmaf(iv, b.z,  fmaf(ivdy, b.w,  acc[p][1]));
                acc[p][2] = fmaf(iv, cc.x, fmaf(ivdy, cc.y, acc[p][2]));
                acc[p][3] = fmaf(iv, cc.z, fmaf(ivdy, cc.w, acc[p][3]));
                acc[p][4] = fmaf(iv, d.x,  fmaf(ivdy, d.y,  acc[p][4]));
                acc[p][5] = fmaf(iv, d.z,  fmaf(ivdy, d.w,  acc[p][5]));
            }
        }
        #pragma unroll
        for (int p = 0; p < 2; ++p) {
            int e = t + (p << 8);
            float ax = 1.f + acc[p][6], ay = acc[p][7];
            float im = frcp(ax*ax + ay*ay);
            float tx = acc[p][2]*acc[p][4] - acc[p][3]*acc[p][5];
            float ty = acc[p][2]*acc[p][5] + acc[p][3]*acc[p][4];
            float wx = acc[p][0] - (tx*ax + ty*ay) * im;
            float wy = acc[p][1] - (ty*ax - tx*ay) * im;
            float2 A = make_float2(wx - tn[p]*wy, wy + tn[p]*wx); // (1+i*tan)*w
            Acm[(c << 9) + e] = A;                 // contiguous store
            b0[e] = A;
        }
        float2* rA = lds_fft_r8<512, 1>(b0, b1, +1.f, twt);
        for (int k = t; k < 512; k += TPB) {
            float ang = PI2F * ((float)(c * k) * invL);
            float sn, cs; __sincosf(ang, &sn, &cs);
            T_K[k * TSTR + c] = cmul(make_float2(cs, sn), rA[k]);
        }
    } else {
        const int c = bx - 512;
        float uv0 = u[c + (t << 9)];
        float uv1 = u[c + ((t + 256) << 9)];
        {
            int n0 = c + (t << 9), n1 = c + ((t + 256) << 9);
            float sn, cs;
            __sincosf(PIF * ((float)n0 * invL), &sn, &cs);
            b0[t]        = make_float2(uv0, 0.f);
            b0[512 + t]  = make_float2(uv0 * cs, -uv0 * sn);
            __sincosf(PIF * ((float)n1 * invL), &sn, &cs);
            b0[t + 256]       = make_float2(uv1, 0.f);
            b0[512 + t + 256] = make_float2(uv1 * cs, -uv1 * sn);
        }
        float2* rU = lds_fft_r8<512, 2>(b0, b1, -1.f, twt);
        for (int i = t; i < 1024; i += TPB) {
            int v = i >> 9, k = i & 511;
            float ang = -PI2F * ((float)(c * k) * invL);
            float sn, cs; __sincosf(ang, &sn, &cs);
            float2 val = cmul(make_float2(cs, sn), rU[(v << 9) + k]);
            if (v == 0) T_U [k * TSTR + c] = val;
            else        T_Uo[k * TSTR + c] = val;
        }
    }
}

// ---- kII: 1536 blocks.
//  b in [0,512): row c=b: T_K p2 (ifft) -> K -> K*tw -> fwd p1 -> T_Ko scatter.
//  b in [512,1024): row c=b-512: T_U p2 -> Ue (contiguous).
//  b in [1024,1536): row c=b-1024: T_Uo p2 -> Uo (contiguous).
__global__ __launch_bounds__(TPB, 4) void kII(
    const float2* __restrict__ T_K, const float2* __restrict__ T_U,
    const float2* __restrict__ T_Uo,
    float2* __restrict__ T_Ko, float2* __restrict__ Ue, float2* __restrict__ Uo)
{
    __shared__ float2 b0[1024], b1[1024];
    __shared__ float2 twt[576];
    const int t = threadIdx.x, bx = blockIdx.x;
    const float invL = 1.0f / (float)L_LEN;
    twt_init(twt);
    if (bx < 512) {
        const int c = bx;
        for (int i = t; i < 512; i += TPB) b0[i] = T_K[c * TSTR + i];
        float2* rK = lds_fft_r8<512, 1>(b0, b1, +1.f, twt);
        float2* o = (rK == b0) ? b1 : b0;
        for (int i = t; i < 512; i += TPB) {
            int n = c + (i << 9);
            float K = rK[i].x * invL;                 // Re(ifft)/L
            float sn, cs; __sincosf(PIF * ((float)n * invL), &sn, &cs);
            o[i] = make_float2(K * cs, -K * sn);      // K * e^{-i pi n/L}
        }
        float2* r2 = lds_fft_r8<512, 1>(o, rK, -1.f, twt);
        for (int k = t; k < 512; k += TPB) {
            float ang = -PI2F * ((float)(c * k) * invL);
            float sn, cs; __sincosf(ang, &sn, &cs);
            T_Ko[k * TSTR + c] = cmul(make_float2(cs, sn), r2[k]);
        }
    } else {
        const int c = (bx & 511);
        const float2* Tin = (bx < 1024) ? T_U : T_Uo;
        float2* Xo        = (bx < 1024) ? Ue  : Uo;
        for (int i = t; i < 512; i += TPB) b0[i] = Tin[c * TSTR + i];
        float2* r = lds_fft_r8<512, 1>(b0, b1, -1.f, twt);
        for (int k = t; k < 512; k += TPB)
            Xo[(c << 9) + k] = r[k];                  // contiguous
    }
}

// ---- kIII: 1024 blocks.
//  b in [0,512): row kc=b: T_Ko p2 -> Ko ; Vo = Uo*Ko ; inv p1 -> T_Vo scatter.
//  b in [512,1024): row kc=b-512: Ve = Ue*Acm ; inv p1 -> T_Ve scatter.
__global__ __launch_bounds__(TPB, 4) void kIII(
    const float2* __restrict__ T_Ko, const float2* __restrict__ Ue,
    const float2* __restrict__ Uo, const float2* __restrict__ Acm,
    float2* __restrict__ T_Ve, float2* __restrict__ T_Vo)
{
    __shared__ float2 b0[1024], b1[1024];
    __shared__ float2 twt[576];
    const int t = threadIdx.x, bx = blockIdx.x;
    const float invL = 1.0f / (float)L_LEN;
    twt_init(twt);
    if (bx < 512) {
        const int kc = bx;
        for (int i = t; i < 512; i += TPB) b0[i] = T_Ko[kc * TSTR + i];
        float2* rKo = lds_fft_r8<512, 1>(b0, b1, -1.f, twt);
        float2* o3 = (rKo == b0) ? b1 : b0;
        for (int i = t; i < 512; i += TPB)
            o3[i] = cmul(Uo[(kc << 9) + i], rKo[i]);  // Vo
        float2* rV = lds_fft_r8<512, 1>(o3, rKo, +1.f, twt);
        for (int k = t; k < 512; k += TPB) {
            float ang = PI2F * ((float)(kc * k) * invL);
            float sn, cs; __sincosf(ang, &sn, &cs);
            T_Vo[k * TSTR + kc] = cmul(make_float2(cs, sn), rV[k]);
        }
    } else {
        const int kc = bx - 512;
        for (int i = t; i < 512; i += TPB)
            b0[i] = cmul(Ue[(kc << 9) + i], Acm[(kc << 9) + i]); // Ve
        float2* rV = lds_fft_r8<512, 1>(b0, b1, +1.f, twt);
        for (int k = t; k < 512; k += TPB) {
            float ang = PI2F * ((float)(kc * k) * invL);
            float sn, cs; __sincosf(ang, &sn, &cs);
            T_Ve[k * TSTR + kc] = cmul(make_float2(cs, sn), rV[k]);
        }
    }
}

// ---- kIV: 512 blocks, one row k/block: inv pass2 (NF=2) + combine + D*u -> out
__global__ __launch_bounds__(TPB, 4) void kIV(
    const float2* __restrict__ T_Ve, const float2* __restrict__ T_Vo,
    const float* __restrict__ u, const float* __restrict__ Dp,
    float* __restrict__ out)
{
    __shared__ float2 b0[1024], b1[1024];
    __shared__ float2 twt[576];
    const int t = threadIdx.x, k = blockIdx.x;
    const float invL = 1.0f / (float)L_LEN;
    twt_init(twt);
    for (int i = t; i < 512; i += TPB) {
        b0[i]       = T_Ve[k * TSTR + i];                   // contiguous
        b0[i + 512] = T_Vo[k * TSTR + i];
    }
    float2* r = lds_fft_r8<512, 2>(b0, b1, +1.f, twt);      // [0,512)=yE, rest yO
    const float sc = 0.5f * invL;                           // 1/(2L)
    const float D = Dp[0];
    for (int o1 = t; o1 < 512; o1 += TPB) {
        int n = k + (o1 << 9);
        float sn, cs; __sincosf(PIF * ((float)n * invL), &sn, &cs);
        float2 yE = r[o1];
        float2 yO = r[o1 + 512];
        // y = (yE.re + Re(e^{+i pi n/L} * yO)) / (2L) + D*u
        out[n] = fmaf(D, u[n], (yE.x + cs * yO.x - sn * yO.y) * sc);
    }
}

extern "C" void kernel_launch(void* const* d_in, const int* in_sizes, int n_in,
                              void* d_out, int out_size, void* d_ws, size_t ws_size,
                              hipStream_t stream) {
    const float* u    = (const float*)d_in[0];
    const float* Lre  = (const float*)d_in[1];
    const float* Lim  = (const float*)d_in[2];
    const float* Pre  = (const float*)d_in[3];
    const float* Pim  = (const float*)d_in[4];
    const float* Bre  = (const float*)d_in[5];
    const float* Bim  = (const float*)d_in[6];
    const float* Cri  = (const float*)d_in[7];
    const float* Dp   = (const float*)d_in[8];
    const float* lstp = (const float*)d_in[9];
    float* out = (float*)d_out;

    // Workspace (~19.7 MB): 512-stride arrays 2MB each; TSTR arrays 0x220000 each
    char* ws = (char*)d_ws;
    float2* Acm  = (float2*)(ws);                    // 512-stride
    float2* Ue   = (float2*)(ws + 0x200000);         // 512-stride
    float2* Uo   = (float2*)(ws + 0x400000);         // 512-stride
    float2* T_K  = (float2*)(ws + 0x600000);         // TSTR-stride
    float2* T_U  = (float2*)(ws + 0x820000);         // TSTR-stride
    float2* T_Uo = (float2*)(ws + 0xA40000);         // TSTR-stride
    float2* T_Ko = (float2*)(ws + 0xC60000);         // TSTR-stride
    float2* T_Ve = (float2*)(ws + 0xE80000);         // TSTR-stride
    float2* T_Vo = (float2*)(ws + 0x10A0000);        // TSTR-stride

    kI  <<<1024, TPB, 0, stream>>>(u, Lre,Lim,Pre,Pim,Bre,Bim,Cri,lstp,
                                   Acm, T_K, T_U, T_Uo);
    kII <<<1536, TPB, 0, stream>>>(T_K, T_U, T_Uo, T_Ko, Ue, Uo);
    kIII<<<1024, TPB, 0, stream>>>(T_Ko, Ue, Uo, Acm, T_Ve, T_Vo);
    kIV <<< 512, TPB, 0, stream>>>(T_Ve, T_Vo, u, Dp, out);
}